// Round 13
// baseline (167.159 us; speedup 1.0000x reference)
//
#include <hip/hip_runtime.h>
#include <math.h>

#define BB 4
#define SS 1024
#define DD 1024
#define HH 16
#define DHH 64

typedef short bf16x8 __attribute__((ext_vector_type(8)));
typedef float f32x4 __attribute__((ext_vector_type(4)));

// fp32 -> bf16 round-to-nearest-even
__device__ __forceinline__ unsigned short f2bf(float f) {
    unsigned u = __float_as_uint(f);
    u += 0x7fffu + ((u >> 16) & 1u);
    return (unsigned short)(u >> 16);
}

// async global->LDS, 16B per lane; LDS dest = wave-uniform base + lane*16.
__device__ __forceinline__ void glds16(const void* g, void* l) {
    __builtin_amdgcn_global_load_lds(
        (const __attribute__((address_space(1))) unsigned int*)g,
        (__attribute__((address_space(3))) unsigned int*)l, 16, 0, 0);
}

// s_waitcnt imm (gfx9): vmcnt lo [3:0], expcnt [6:4], lgkmcnt [11:8], vmcnt hi [15:14].
#define WAITCNT_VM(n)  (0xF70 | (n))     // lgkm/exp nowait, vmcnt = n
#define WAITCNT_LGKM0  (0xC07F)          // lgkmcnt(0), vmcnt/exp nowait

// 32B-granule XOR swizzle (rows padded to 80 shorts) — attention LDS.
__device__ __forceinline__ int swz(int row, int col) {
    return ((((col >> 4) ^ (row >> 2)) & 3) << 4) | (col & 15);
}

// XCD-chunked block swizzle (m157, bijective when NWG%8==0).
#define XCD_REMAP(flat, NWG) (((flat) & 7) * ((NWG) >> 3) + ((flat) >> 3))

// ---------------------------------------------------------------------------
// Fused prologue (R8): blocks [0,4096) cast X fp32->bf16; [4096,4864)
// transpose-cast W1; [4864,5120) transpose-cast W2.
// ---------------------------------------------------------------------------
__global__ __launch_bounds__(256) void prologue_kernel(
    const float* __restrict__ x, const float* __restrict__ w1,
    const float* __restrict__ w2, unsigned short* __restrict__ Xb,
    unsigned short* __restrict__ W1t, unsigned short* __restrict__ W2t)
{
    __shared__ float tile[64][65];
    const int bx = blockIdx.x;
    if (bx < 4096) {
        int i = bx * 256 + threadIdx.x;
        float4 v = ((const float4*)x)[i];
        ushort4 o = { f2bf(v.x), f2bf(v.y), f2bf(v.z), f2bf(v.w) };
        ((ushort4*)Xb)[i] = o;
        return;
    }
    const float* W; unsigned short* Wt; int N, n0, k0;
    if (bx < 4864) {
        int id = bx - 4096; W = w1; Wt = W1t; N = 3072;
        n0 = (id % 48) * 64; k0 = (id / 48) * 64;
    } else {
        int id = bx - 4864; W = w2; Wt = W2t; N = 1024;
        n0 = (id & 15) * 64; k0 = (id >> 4) * 64;
    }
    int c = threadIdx.x & 63, r0 = threadIdx.x >> 6;
    #pragma unroll
    for (int i = 0; i < 16; ++i) {
        int r = r0 + i * 4;
        tile[r][c] = W[(size_t)(k0 + r) * N + n0 + c];
    }
    __syncthreads();
    #pragma unroll
    for (int i = 0; i < 16; ++i) {
        int r = r0 + i * 4;  // n-local
        Wt[(size_t)(n0 + r) * 1024 + k0 + c] = f2bf(tile[c][r]);
    }
}

// ---------------------------------------------------------------------------
// QKV GEMM (R29 = R28 + m201 mid-phase barrier): 256x192 tile, 256 blocks,
// 1024 threads (16 waves, 4/SIMD). Phase shape now
//   {ds_reads(p); stage(p+1); BARRIER; MFMA(p); counted vmcnt; BARRIER}
// — fragment-read latency drains inside the first barrier's sync window
// instead of sitting on each wave's MFMA dependency chain (m201/m196
// "per-phase interleave is the lever"). Ledger unchanged from R28:
// read(p) valid after phase p-1's vmcnt+barrier; stage(p+1) WAR window
// >= 2 barriers; counted vmcnt c=(w<12?2:1) never drains mid-loop.
// ---------------------------------------------------------------------------
__global__ __launch_bounds__(1024) void gemm_mfma(
    const unsigned short* __restrict__ A,
    const unsigned short* __restrict__ Bt,
    const float* __restrict__ bias,
    unsigned short* __restrict__ Cout,
    unsigned short* __restrict__ Vt,
    int N, int K)
{
    __shared__ unsigned short smem[65536];   // 128 KB: 4 regions x 16384 shorts

    const int t = threadIdx.x;
    const int lane = t & 63;
    const int w = t >> 6;                    // 0..15
    const int l15 = lane & 15, quad = lane >> 4;
    const int wr = w >> 2, wc = w & 3;       // 4M x 4N; per-wave 64x48

    // XCD-chunked remap: 256 blocks, 32/XCD = 2 tm-rows of 16.
    const int flat = XCD_REMAP(blockIdx.y * 16 + blockIdx.x, 256);
    const int tm = flat >> 4, tn = flat & 15;
    const int bm = tm * 256, bn = tn * 192;

    // staging lane math (R24 proven): linear LDS dest, inverse-swizzled
    // per-lane global source. pair-row p = w*8 + (lane>>3); p&7 = lane>>3.
    const int sl_ca  = ((lane & 7) ^ (lane >> 3)) << 4;
    const int sl_odd = (sl_ca >= 64);
    const int sl_k   = (sl_ca & 63) >> 1;
    const int pr  = w * 8 + (lane >> 3);             // 0..127 pair index
    const int prB = (pr < 96) ? pr : 95;             // clamp (w>=12 unused)

    const unsigned short* Asrc = A  + (size_t)(bm + 2 * pr  + sl_odd) * K + sl_k;
    const unsigned short* Bsrc = Bt + (size_t)(bn + 2 * prB + sl_odd) * K + sl_k;

    // stage one 32KB region (tile, K-half kh) into buffer buf.
    auto stage = [&](int tile, int kh, int buf) {
        const int toff = tile * 64 + kh * 32;
        const int rb = (buf * 2 + kh) * 16384;       // region base (shorts)
        glds16(Asrc + toff, &smem[rb + w * 512]);            // A: 16 KB
        if (w < 12)
            glds16(Bsrc + toff, &smem[rb + 8192 + w * 512]); // B: 12 KB real
    };

    const f32x4 zero4 = {0.f, 0.f, 0.f, 0.f};
    f32x4 acc[4][3];
    #pragma unroll
    for (int i = 0; i < 4; ++i)
        #pragma unroll
        for (int j = 0; j < 3; ++j) acc[i][j] = zero4;

    const int T = K / 64;                    // 16 K-tiles

    // prologue: tile0 both K-halves; retire region(0,0), keep (0,1) in flight
    stage(0, 0, 0);
    stage(0, 1, 0);
    if (w < 12) __builtin_amdgcn_s_waitcnt(WAITCNT_VM(2));
    else        __builtin_amdgcn_s_waitcnt(WAITCNT_VM(1));
    __builtin_amdgcn_s_barrier();
    __builtin_amdgcn_sched_barrier(0);

    for (int tt = 0; tt < T; ++tt) {
        const int buf = tt & 1;
        #pragma unroll
        for (int kh = 0; kh < 2; ++kh) {
            const int rb = (buf * 2 + kh) * 16384;

            bf16x8 af[4], bfr[3];
            #pragma unroll
            for (int i = 0; i < 4; ++i) {
                int ar = wr * 64 + i * 16 + l15;     // 0..255
                int byte = (ar >> 1) * 128 + (ar & 1) * 64 + (quad << 4);
                byte ^= ((ar >> 1) & 7) << 4;        // pair-row swizzle
                af[i] = *(const bf16x8*)&smem[rb + (byte >> 1)];
            }
            #pragma unroll
            for (int nj = 0; nj < 3; ++nj) {
                int br = wc * 48 + nj * 16 + l15;    // 0..191
                int byte = (br >> 1) * 128 + (br & 1) * 64 + (quad << 4);
                byte ^= ((br >> 1) & 7) << 4;
                bfr[nj] = *(const bf16x8*)&smem[rb + 8192 + (byte >> 1)];
            }

            if (tt + 1 < T) stage(tt + 1, kh, buf ^ 1);

            // m201 mid-phase barrier: read latency drains in the sync window;
            // MFMAs of all waves launch from ready registers.
            __builtin_amdgcn_s_barrier();
            __builtin_amdgcn_sched_barrier(0);

            __builtin_amdgcn_s_setprio(1);
            #pragma unroll
            for (int i = 0; i < 4; ++i)
                #pragma unroll
                for (int nj = 0; nj < 3; ++nj)
                    acc[i][nj] = __builtin_amdgcn_mfma_f32_16x16x32_bf16(
                        af[i], bfr[nj], acc[i][nj], 0, 0, 0);
            __builtin_amdgcn_s_setprio(0);

            // retire the region needed NEXT phase; keep newest in flight.
            if (tt + 1 < T) {
                if (w < 12) __builtin_amdgcn_s_waitcnt(WAITCNT_VM(2));
                else        __builtin_amdgcn_s_waitcnt(WAITCNT_VM(1));
            } else {
                __builtin_amdgcn_s_waitcnt(WAITCNT_VM(0));
            }
            __builtin_amdgcn_s_barrier();
            __builtin_amdgcn_sched_barrier(0);
        }
    }

    __syncthreads();   // reuse smem for epilogue staging

    float bv[3];
    #pragma unroll
    for (int nj = 0; nj < 3; ++nj) bv[nj] = bias[bn + wc * 48 + nj * 16 + l15];

    const int b = bm >> 10, s0 = bm & 1023;

    if (tn <= 9) {
        // pure QK: direct [256][192]
        #pragma unroll
        for (int mi = 0; mi < 4; ++mi)
            #pragma unroll
            for (int nj = 0; nj < 3; ++nj)
                #pragma unroll
                for (int r = 0; r < 4; ++r) {
                    int row = wr * 64 + mi * 16 + quad * 4 + r;
                    int col = wc * 48 + nj * 16 + l15;
                    smem[row * 192 + (col ^ (((row >> 2) & 3) << 4))] =
                        f2bf(acc[mi][nj][r] + bv[nj]);
                }
        __syncthreads();
        #pragma unroll
        for (int it = 0; it < 6; ++it) {
            int chunk = it * 1024 + t;           // 6144 chunks of 8
            int row = chunk / 24;
            int col = (chunk % 24) * 8;
            bf16x8 val = *(const bf16x8*)&smem[row * 192 +
                         (col ^ (((row >> 2) & 3) << 4))];
            *(bf16x8*)&Cout[(size_t)(bm + row) * N + bn + col] = val;
        }
    } else if (tn >= 11) {
        // pure V: transposed [192 cols][256 rows] -> Vt[bh][dh][s]
        #pragma unroll
        for (int mi = 0; mi < 4; ++mi)
            #pragma unroll
            for (int nj = 0; nj < 3; ++nj)
                #pragma unroll
                for (int r = 0; r < 4; ++r) {
                    int row = wr * 64 + mi * 16 + quad * 4 + r;     // s-local
                    int col = wc * 48 + nj * 16 + l15;              // n-local
                    smem[col * 256 + (row ^ (((col >> 2) & 3) << 4))] =
                        f2bf(acc[mi][nj][r] + bv[nj]);
                }
        __syncthreads();
        int h0 = (bn - 2048) >> 6;
        #pragma unroll
        for (int it = 0; it < 6; ++it) {
            int chunk = it * 1024 + t;           // 6144 chunks of 8
            int col = chunk >> 5;                // 0..191
            int r8 = (chunk & 31) * 8;
            bf16x8 val = *(const bf16x8*)&smem[col * 256 +
                         (r8 ^ (((col >> 2) & 3) << 4))];
            int h = h0 + (col >> 6), dh = col & 63;
            *(bf16x8*)&Vt[(((size_t)b * 16 + h) * 64 + dh) * 1024 + s0 + r8] = val;
        }
    } else {
        // straddle (bn=1920): cols 0-127 QK direct; cols 128-191 V transposed
        #pragma unroll
        for (int mi = 0; mi < 4; ++mi)
            #pragma unroll
            for (int nj = 0; nj < 3; ++nj)
                #pragma unroll
                for (int r = 0; r < 4; ++r) {
                    int row = wr * 64 + mi * 16 + quad * 4 + r;
                    int col = wc * 48 + nj * 16 + l15;
                    unsigned short v = f2bf(acc[mi][nj][r] + bv[nj]);
                    if (col < 128)
                        smem[row * 128 + (col ^ (((row >> 2) & 3) << 4))] = v;
                    else {
                        int vc = col - 128;
                        smem[32768 + vc * 256 + (row ^ (((vc >> 2) & 3) << 4))] = v;
                    }
                }
        __syncthreads();
        #pragma unroll
        for (int it = 0; it < 4; ++it) {         // QK: 256x128 = 4096 chunks
            int chunk = it * 1024 + t;
            int row = chunk >> 4;
            int col = (chunk & 15) * 8;
            bf16x8 val = *(const bf16x8*)&smem[row * 128 +
                         (col ^ (((row >> 2) & 3) << 4))];
            *(bf16x8*)&Cout[(size_t)(bm + row) * N + bn + col] = val;
        }
        #pragma unroll
        for (int it = 0; it < 2; ++it) {         // V: 64x256 = 2048 chunks
            int chunk = it * 1024 + t;
            int vc = chunk >> 5;                 // 0..63 -> dh
            int r8 = (chunk & 31) * 8;
            bf16x8 val = *(const bf16x8*)&smem[32768 + vc * 256 +
                         (r8 ^ (((vc >> 2) & 3) << 4))];
            *(bf16x8*)&Vt[(((size_t)b * 16 + 0) * 64 + vc) * 1024 + s0 + r8] = val;
        }
    }
}

// ---------------------------------------------------------------------------
// Output-projection GEMM (R16 proven + XCD swizzle): TRIPLE-BUFFERED,
// 64x128 tile, BK=32, 512 blocks (2/CU), vmcnt(6) partial wait.
// ---------------------------------------------------------------------------
__global__ __launch_bounds__(256) void gemm2_mfma(
    const unsigned short* __restrict__ A,
    const unsigned short* __restrict__ Bt,
    const float* __restrict__ bias,
    float* __restrict__ C,
    int N, int K)
{
    __shared__ unsigned short smem[18432];   // 3 bufs x 12 KB; fp32 epi 32 KB fits

    const int t = threadIdx.x;
    const int lane = t & 63;
    const int w = t >> 6;
    const int l15 = lane & 15, quad = lane >> 4;

    const int flat = XCD_REMAP(blockIdx.y * 8 + blockIdx.x, 512);
    const int bm = (flat / 8) * 64, bn = (flat % 8) * 128;

    const int fragoff = l15 * K + quad * 8;

    const f32x4 zero4 = {0.f, 0.f, 0.f, 0.f};
    f32x4 acc[2][4];
    #pragma unroll
    for (int i = 0; i < 2; ++i)
        #pragma unroll
        for (int j = 0; j < 4; ++j) acc[i][j] = zero4;

    const unsigned short* Abase = A  + (size_t)bm * K + fragoff;
    const unsigned short* Bbase = Bt + (size_t)bn * K + fragoff;

    const int R = K / 32;

    auto issue = [&](int k, int b) {
        glds16(Abase + (size_t)(w * 16) * K + k * 32,
               &smem[b * 6144 + w * 512]);
        #pragma unroll
        for (int g2 = 0; g2 < 2; ++g2) {
            int g = w * 2 + g2;
            glds16(Bbase + (size_t)(g * 16) * K + k * 32,
                   &smem[b * 6144 + 2048 + g * 512]);
        }
    };

    issue(0, 0);
    issue(1, 1);
    for (int k = 0; k < R; ++k) {
        if (k + 2 < R) {
            issue(k + 2, (k + 2) % 3);
            __builtin_amdgcn_s_waitcnt(WAITCNT_VM(6));
        } else if (k + 1 < R) {
            __builtin_amdgcn_s_waitcnt(WAITCNT_VM(3));
        } else {
            __builtin_amdgcn_s_waitcnt(WAITCNT_VM(0));
        }
        __builtin_amdgcn_s_barrier();

        bf16x8 af[2], bfr[4];
        #pragma unroll
        for (int mi = 0; mi < 2; ++mi)
            af[mi] = *(const bf16x8*)&smem[(k % 3) * 6144 + ((w >> 1) * 2 + mi) * 512 + lane * 8];
        #pragma unroll
        for (int nj = 0; nj < 4; ++nj)
            bfr[nj] = *(const bf16x8*)&smem[(k % 3) * 6144 + 2048 + ((w & 1) * 4 + nj) * 512 + lane * 8];
        #pragma unroll
        for (int mi = 0; mi < 2; ++mi)
            #pragma unroll
            for (int nj = 0; nj < 4; ++nj)
                acc[mi][nj] = __builtin_amdgcn_mfma_f32_16x16x32_bf16(
                    af[mi], bfr[nj], acc[mi][nj], 0, 0, 0);

        __builtin_amdgcn_s_barrier();
    }

    const int wm = (w >> 1) * 32;
    const int wn = (w & 1) * 64;
    float bv[4];
    #pragma unroll
    for (int nj = 0; nj < 4; ++nj) bv[nj] = bias[bn + wn + nj * 16 + l15];

    float* fs = (float*)smem;
    #pragma unroll
    for (int mi = 0; mi < 2; ++mi)
        #pragma unroll
        for (int nj = 0; nj < 4; ++nj)
            #pragma unroll
            for (int r = 0; r < 4; ++r)
                fs[(wm + mi * 16 + quad * 4 + r) * 128 + wn + nj * 16 + l15] =
                    acc[mi][nj][r] + bv[nj];
    __syncthreads();
    #pragma unroll
    for (int i = 0; i < 8; ++i) {
        int off = i * 256 + t;
        int row = off >> 5, col = (off & 31) * 4;
        *(float4*)&C[(size_t)(bm + row) * N + bn + col] =
            *(const float4*)&fs[row * 128 + col];
    }
}

// ---------------------------------------------------------------------------
// Flash attention (R26, proven): DOUBLE-BUFFERED K/V LDS, one barrier/round.
// ---------------------------------------------------------------------------
__device__ __forceinline__ void attn_tile_step8(
    bf16x8 q0, bf16x8 q1, float* lsum, f32x4* o,
    const unsigned short (*Ks)[80], const unsigned short (*VsT)[80],
    unsigned short (*Ps)[80],
    int wq, int l15, int quad, bool diag)
{
    const f32x4 zero4 = {0.f, 0.f, 0.f, 0.f};
    // S = Q K^T
    f32x4 s[4];
    #pragma unroll
    for (int nj = 0; nj < 4; ++nj) {
        int n = nj * 16 + l15;
        f32x4 sa = zero4;
        bf16x8 b0 = *(const bf16x8*)&Ks[n][swz(n, quad * 8)];
        bf16x8 b1 = *(const bf16x8*)&Ks[n][swz(n, 32 + quad * 8)];
        sa = __builtin_amdgcn_mfma_f32_16x16x32_bf16(q0, b0, sa, 0, 0, 0);
        sa = __builtin_amdgcn_mfma_f32_16x16x32_bf16(q1, b1, sa, 0, 0, 0);
        s[nj] = sa;
    }
    const float scale = 0.125f;  // 1/sqrt(64)

    // p = exp(s*scale); masked -> 0. Lane-private l partials (no shfl here).
    #pragma unroll
    for (int nj = 0; nj < 4; ++nj)
        #pragma unroll
        for (int r = 0; r < 4; ++r) {
            float sv = s[nj][r] * scale;
            if (diag && (nj * 16 + l15) > (wq * 16 + quad * 4 + r)) sv = -INFINITY;
            float p = __expf(sv);
            lsum[r] += p;
            int qloc = wq * 16 + quad * 4 + r;
            Ps[qloc][swz(qloc, nj * 16 + l15)] = f2bf(p);
        }

    // O += P @ V
    #pragma unroll
    for (int kk = 0; kk < 2; ++kk) {
        int m = wq * 16 + l15;
        bf16x8 pa = *(const bf16x8*)&Ps[m][swz(m, kk * 32 + quad * 8)];
        #pragma unroll
        for (int nj = 0; nj < 4; ++nj) {
            int n = nj * 16 + l15;
            bf16x8 vb = *(const bf16x8*)&VsT[n][swz(n, kk * 32 + quad * 8)];
            o[nj] = __builtin_amdgcn_mfma_f32_16x16x32_bf16(pa, vb, o[nj], 0, 0, 0);
        }
    }
}

__global__ __launch_bounds__(512) void attn_mfma(
    const unsigned short* __restrict__ qkv,  // [B*S][3072] bf16
    const unsigned short* __restrict__ Vt,   // [bh][64][1024] bf16
    unsigned short* __restrict__ aout)       // [B*S][1024] bf16
{
    __shared__ unsigned short Ks[2][64][80];   // 20 KB (double-buffered)
    __shared__ unsigned short VsT[2][64][80];  // 20 KB (double-buffered)
    __shared__ unsigned short Ps[2][64][80];   // 20 KB (per tile-group)

    const int t = threadIdx.x;
    const int lane = t & 63;
    const int wave = t >> 6;           // 0..7
    const int wq = wave & 3;
    const int tile = wave >> 2;        // 0 = qlo, 1 = qhi
    const int l15 = lane & 15, quad = lane >> 4;

    const int flat = XCD_REMAP(blockIdx.y * 8 + blockIdx.x, 512);
    const int qlo = flat % 8;          // 0..7
    const int bh = flat / 8;           // 0..63

    const int qhi = 15 - qlo;          // 15..8
    const int qb = tile ? qhi : qlo;
    const int b = bh >> 4, h = bh & 15;
    const size_t qkvbase = (size_t)b * SS * 3072;
    const f32x4 zero4 = {0.f, 0.f, 0.f, 0.f};

    bf16x8 qf0, qf1;
    {
        const unsigned short* p = qkv + qkvbase +
            (size_t)(qb * 64 + wq * 16 + l15) * 3072 + h * 64 + quad * 8;
        qf0 = *(const bf16x8*)p;
        qf1 = *(const bf16x8*)(p + 32);
    }

    float lsum[4];
    f32x4 o[4];
    #pragma unroll
    for (int r = 0; r < 4; ++r) lsum[r] = 0.f;
    #pragma unroll
    for (int nj = 0; nj < 4; ++nj) o[nj] = zero4;

    // register-prefetch staging: 512 threads cover 64x64 in one 16B op each
    const int sr = t >> 3, scc = (t & 7) * 8;
    const unsigned short* kgp = qkv + qkvbase + 1024 + h * 64 + (size_t)sr * 3072 + scc;
    const unsigned short* vgp = Vt + ((size_t)bh * 64 + sr) * 1024 + scc;
    const int klds = swz(sr, scc);     // same swizzled offset for K and V rows
    bf16x8 kreg, vreg;

    // prologue: round 0 into buf0; prefetch round 1 (qhi >= 8 always)
    kreg = *(const bf16x8*)(kgp);
    vreg = *(const bf16x8*)(vgp);
    *(bf16x8*)&Ks[0][sr][klds] = kreg;
    *(bf16x8*)&VsT[0][sr][klds] = vreg;
    kreg = *(const bf16x8*)(kgp + (size_t)64 * 3072);
    vreg = *(const bf16x8*)(vgp + 64);
    __builtin_amdgcn_s_waitcnt(WAITCNT_LGKM0);
    __builtin_amdgcn_s_barrier();

    for (int kb = 0; kb <= qhi; ++kb) {
        const int cur = kb & 1;
        if (kb < qhi) {
            // write prefetched round kb+1 into the other buffer (its last
            // readers were round kb-1 — protected by the trailing barrier)
            *(bf16x8*)&Ks[cur ^ 1][sr][klds] = kreg;
            *(bf16x8*)&VsT[cur ^ 1][sr][klds] = vreg;
            if (kb + 1 < qhi) {                // issue round kb+2 loads
                kreg = *(const bf16x8*)(kgp + (size_t)(kb + 2) * 64 * 3072);
                vreg = *(const bf16x8*)(vgp + (kb + 2) * 64);
            }
        }
        if (kb <= qb)
            attn_tile_step8(qf0, qf1, lsum, o, Ks[cur], VsT[cur], Ps[tile],
                            wq, l15, quad, kb == qb);
        __builtin_amdgcn_s_waitcnt(WAITCNT_LGKM0);  // writes visible
        __builtin_amdgcn_s_barrier();               // one barrier per round
    }

    // deferred l-reduction: one shfl pass over the 16 l15 lanes
    #pragma unroll
    for (int off = 1; off < 16; off <<= 1)
        #pragma unroll
        for (int r = 0; r < 4; ++r)
            lsum[r] += __shfl_xor(lsum[r], off);

    // epilogue: normalize, write merge-heads bf16 [B*S][1024]
    #pragma unroll
    for (int r = 0; r < 4; ++r) {
        float inv = 1.0f / lsum[r];
        int rloc = wq * 16 + quad * 4 + r;
        size_t ob = ((size_t)b * SS + qb * 64 + rloc) * 1024 + h * 64;
        #pragma unroll
        for (int nj = 0; nj < 4; ++nj)
            aout[ob + nj * 16 + l15] = f2bf(o[nj][r] * inv);
    }
}

extern "C" void kernel_launch(void* const* d_in, const int* in_sizes, int n_in,
                              void* d_out, int out_size, void* d_ws, size_t ws_size,
                              hipStream_t stream)
{
    const float* x     = (const float*)d_in[0];
    const float* wqkv  = (const float*)d_in[1];
    const float* bqkv  = (const float*)d_in[2];
    const float* wproj = (const float*)d_in[3];
    const float* bproj = (const float*)d_in[4];
    float* out = (float*)d_out;

    unsigned short* ws   = (unsigned short*)d_ws;
    unsigned short* Xb   = ws;                                  // 4096*1024
    unsigned short* W1t  = Xb  + (size_t)4096 * 1024;           // 3072*1024
    unsigned short* W2t  = W1t + (size_t)3072 * 1024;           // 1024*1024
    unsigned short* qkv  = W2t + (size_t)1024 * 1024;           // 4096*3072 (V third unused)
    unsigned short* Vt   = qkv + (size_t)4096 * 3072;           // 64*64*1024
    unsigned short* abuf = Vt  + (size_t)64 * 64 * 1024;        // 4096*1024

    prologue_kernel<<<5120, 256, 0, stream>>>(x, wqkv, wproj, Xb, W1t, W2t);

    // QKV projection: 256x192 tile, 1024 threads, m201 mid-phase barrier
    gemm_mfma<<<dim3(16, 16), 1024, 0, stream>>>(
        Xb, W1t, bqkv, qkv, Vt, 3072, 1024);

    // 8-wave attention: K/V double-buffered, one barrier per round
    attn_mfma<<<dim3(8, 64), 512, 0, stream>>>(qkv, Vt, abuf);

    // Output projection (triple-buffered pipeline) + XCD swizzle
    gemm2_mfma<<<dim3(1024 / 128, 4096 / 64), 256, 0, stream>>>(
        abuf, W2t, bproj, out, 1024, 1024);
}

// Round 14
// 161.413 us; speedup vs baseline: 1.0356x; 1.0356x over previous
//
#include <hip/hip_runtime.h>
#include <math.h>

#define BB 4
#define SS 1024
#define DD 1024
#define HH 16
#define DHH 64

typedef short bf16x8 __attribute__((ext_vector_type(8)));
typedef float f32x4 __attribute__((ext_vector_type(4)));

// fp32 -> bf16 round-to-nearest-even
__device__ __forceinline__ unsigned short f2bf(float f) {
    unsigned u = __float_as_uint(f);
    u += 0x7fffu + ((u >> 16) & 1u);
    return (unsigned short)(u >> 16);
}

// async global->LDS, 16B per lane; LDS dest = wave-uniform base + lane*16.
__device__ __forceinline__ void glds16(const void* g, void* l) {
    __builtin_amdgcn_global_load_lds(
        (const __attribute__((address_space(1))) unsigned int*)g,
        (__attribute__((address_space(3))) unsigned int*)l, 16, 0, 0);
}

// s_waitcnt imm (gfx9): vmcnt lo [3:0], expcnt [6:4], lgkmcnt [11:8], vmcnt hi [15:14].
#define WAITCNT_VM(n)  (0xF70 | (n))     // lgkm/exp nowait, vmcnt = n
#define WAITCNT_LGKM0  (0xC07F)          // lgkmcnt(0), vmcnt/exp nowait

// 32B-granule XOR swizzle (rows padded to 80 shorts) — attention LDS.
__device__ __forceinline__ int swz(int row, int col) {
    return ((((col >> 4) ^ (row >> 2)) & 3) << 4) | (col & 15);
}

// XCD-chunked block swizzle (m157, bijective when NWG%8==0).
#define XCD_REMAP(flat, NWG) (((flat) & 7) * ((NWG) >> 3) + ((flat) >> 3))

// ---------------------------------------------------------------------------
// Fused prologue (R8): blocks [0,4096) cast X fp32->bf16; [4096,4864)
// transpose-cast W1; [4864,5120) transpose-cast W2.
// ---------------------------------------------------------------------------
__global__ __launch_bounds__(256) void prologue_kernel(
    const float* __restrict__ x, const float* __restrict__ w1,
    const float* __restrict__ w2, unsigned short* __restrict__ Xb,
    unsigned short* __restrict__ W1t, unsigned short* __restrict__ W2t)
{
    __shared__ float tile[64][65];
    const int bx = blockIdx.x;
    if (bx < 4096) {
        int i = bx * 256 + threadIdx.x;
        float4 v = ((const float4*)x)[i];
        ushort4 o = { f2bf(v.x), f2bf(v.y), f2bf(v.z), f2bf(v.w) };
        ((ushort4*)Xb)[i] = o;
        return;
    }
    const float* W; unsigned short* Wt; int N, n0, k0;
    if (bx < 4864) {
        int id = bx - 4096; W = w1; Wt = W1t; N = 3072;
        n0 = (id % 48) * 64; k0 = (id / 48) * 64;
    } else {
        int id = bx - 4864; W = w2; Wt = W2t; N = 1024;
        n0 = (id & 15) * 64; k0 = (id >> 4) * 64;
    }
    int c = threadIdx.x & 63, r0 = threadIdx.x >> 6;
    #pragma unroll
    for (int i = 0; i < 16; ++i) {
        int r = r0 + i * 4;
        tile[r][c] = W[(size_t)(k0 + r) * N + n0 + c];
    }
    __syncthreads();
    #pragma unroll
    for (int i = 0; i < 16; ++i) {
        int r = r0 + i * 4;  // n-local
        Wt[(size_t)(n0 + r) * 1024 + k0 + c] = f2bf(tile[c][r]);
    }
}

// ---------------------------------------------------------------------------
// QKV GEMM (R28, reverted from R13's mid-phase barrier — that barrier
// re-aligned all 16 waves every phase and destroyed the natural cross-wave
// stagger that covers ds_read latency at 4 waves/SIMD; −5.3 us measured):
// 256x192 tile, 256 blocks, 1024 threads (16 waves, 4/SIMD).
// Phase = {ds_reads; stage(p+1); MFMA; counted vmcnt; barrier}.
// ---------------------------------------------------------------------------
__global__ __launch_bounds__(1024) void gemm_mfma(
    const unsigned short* __restrict__ A,
    const unsigned short* __restrict__ Bt,
    const float* __restrict__ bias,
    unsigned short* __restrict__ Cout,
    unsigned short* __restrict__ Vt,
    int N, int K)
{
    __shared__ unsigned short smem[65536];   // 128 KB: 4 regions x 16384 shorts

    const int t = threadIdx.x;
    const int lane = t & 63;
    const int w = t >> 6;                    // 0..15
    const int l15 = lane & 15, quad = lane >> 4;
    const int wr = w >> 2, wc = w & 3;       // 4M x 4N; per-wave 64x48

    // XCD-chunked remap: 256 blocks, 32/XCD = 2 tm-rows of 16.
    const int flat = XCD_REMAP(blockIdx.y * 16 + blockIdx.x, 256);
    const int tm = flat >> 4, tn = flat & 15;
    const int bm = tm * 256, bn = tn * 192;

    // staging lane math (R24 proven): linear LDS dest, inverse-swizzled
    // per-lane global source. pair-row p = w*8 + (lane>>3); p&7 = lane>>3.
    const int sl_ca  = ((lane & 7) ^ (lane >> 3)) << 4;
    const int sl_odd = (sl_ca >= 64);
    const int sl_k   = (sl_ca & 63) >> 1;
    const int pr  = w * 8 + (lane >> 3);             // 0..127 pair index
    const int prB = (pr < 96) ? pr : 95;             // clamp (w>=12 unused)

    const unsigned short* Asrc = A  + (size_t)(bm + 2 * pr  + sl_odd) * K + sl_k;
    const unsigned short* Bsrc = Bt + (size_t)(bn + 2 * prB + sl_odd) * K + sl_k;

    // stage one 32KB region (tile, K-half kh) into buffer buf.
    auto stage = [&](int tile, int kh, int buf) {
        const int toff = tile * 64 + kh * 32;
        const int rb = (buf * 2 + kh) * 16384;       // region base (shorts)
        glds16(Asrc + toff, &smem[rb + w * 512]);            // A: 16 KB
        if (w < 12)
            glds16(Bsrc + toff, &smem[rb + 8192 + w * 512]); // B: 12 KB real
    };

    const f32x4 zero4 = {0.f, 0.f, 0.f, 0.f};
    f32x4 acc[4][3];
    #pragma unroll
    for (int i = 0; i < 4; ++i)
        #pragma unroll
        for (int j = 0; j < 3; ++j) acc[i][j] = zero4;

    const int T = K / 64;                    // 16 K-tiles

    // prologue: tile0 both K-halves; retire region(0,0), keep (0,1) in flight
    stage(0, 0, 0);
    stage(0, 1, 0);
    if (w < 12) __builtin_amdgcn_s_waitcnt(WAITCNT_VM(2));
    else        __builtin_amdgcn_s_waitcnt(WAITCNT_VM(1));
    __builtin_amdgcn_s_barrier();
    __builtin_amdgcn_sched_barrier(0);

    for (int tt = 0; tt < T; ++tt) {
        const int buf = tt & 1;
        #pragma unroll
        for (int kh = 0; kh < 2; ++kh) {
            const int rb = (buf * 2 + kh) * 16384;

            bf16x8 af[4], bfr[3];
            #pragma unroll
            for (int i = 0; i < 4; ++i) {
                int ar = wr * 64 + i * 16 + l15;     // 0..255
                int byte = (ar >> 1) * 128 + (ar & 1) * 64 + (quad << 4);
                byte ^= ((ar >> 1) & 7) << 4;        // pair-row swizzle
                af[i] = *(const bf16x8*)&smem[rb + (byte >> 1)];
            }
            #pragma unroll
            for (int nj = 0; nj < 3; ++nj) {
                int br = wc * 48 + nj * 16 + l15;    // 0..191
                int byte = (br >> 1) * 128 + (br & 1) * 64 + (quad << 4);
                byte ^= ((br >> 1) & 7) << 4;
                bfr[nj] = *(const bf16x8*)&smem[rb + 8192 + (byte >> 1)];
            }

            if (tt + 1 < T) stage(tt + 1, kh, buf ^ 1);

            __builtin_amdgcn_s_setprio(1);
            #pragma unroll
            for (int i = 0; i < 4; ++i)
                #pragma unroll
                for (int nj = 0; nj < 3; ++nj)
                    acc[i][nj] = __builtin_amdgcn_mfma_f32_16x16x32_bf16(
                        af[i], bfr[nj], acc[i][nj], 0, 0, 0);
            __builtin_amdgcn_s_setprio(0);

            // retire the region needed NEXT phase; keep newest in flight.
            if (tt + 1 < T) {
                if (w < 12) __builtin_amdgcn_s_waitcnt(WAITCNT_VM(2));
                else        __builtin_amdgcn_s_waitcnt(WAITCNT_VM(1));
            } else {
                __builtin_amdgcn_s_waitcnt(WAITCNT_VM(0));
            }
            __builtin_amdgcn_s_barrier();
            __builtin_amdgcn_sched_barrier(0);
        }
    }

    __syncthreads();   // reuse smem for epilogue staging

    float bv[3];
    #pragma unroll
    for (int nj = 0; nj < 3; ++nj) bv[nj] = bias[bn + wc * 48 + nj * 16 + l15];

    const int b = bm >> 10, s0 = bm & 1023;

    if (tn <= 9) {
        // pure QK: direct [256][192]
        #pragma unroll
        for (int mi = 0; mi < 4; ++mi)
            #pragma unroll
            for (int nj = 0; nj < 3; ++nj)
                #pragma unroll
                for (int r = 0; r < 4; ++r) {
                    int row = wr * 64 + mi * 16 + quad * 4 + r;
                    int col = wc * 48 + nj * 16 + l15;
                    smem[row * 192 + (col ^ (((row >> 2) & 3) << 4))] =
                        f2bf(acc[mi][nj][r] + bv[nj]);
                }
        __syncthreads();
        #pragma unroll
        for (int it = 0; it < 6; ++it) {
            int chunk = it * 1024 + t;           // 6144 chunks of 8
            int row = chunk / 24;
            int col = (chunk % 24) * 8;
            bf16x8 val = *(const bf16x8*)&smem[row * 192 +
                         (col ^ (((row >> 2) & 3) << 4))];
            *(bf16x8*)&Cout[(size_t)(bm + row) * N + bn + col] = val;
        }
    } else if (tn >= 11) {
        // pure V: transposed [192 cols][256 rows] -> Vt[bh][dh][s]
        #pragma unroll
        for (int mi = 0; mi < 4; ++mi)
            #pragma unroll
            for (int nj = 0; nj < 3; ++nj)
                #pragma unroll
                for (int r = 0; r < 4; ++r) {
                    int row = wr * 64 + mi * 16 + quad * 4 + r;     // s-local
                    int col = wc * 48 + nj * 16 + l15;              // n-local
                    smem[col * 256 + (row ^ (((col >> 2) & 3) << 4))] =
                        f2bf(acc[mi][nj][r] + bv[nj]);
                }
        __syncthreads();
        int h0 = (bn - 2048) >> 6;
        #pragma unroll
        for (int it = 0; it < 6; ++it) {
            int chunk = it * 1024 + t;           // 6144 chunks of 8
            int col = chunk >> 5;                // 0..191
            int r8 = (chunk & 31) * 8;
            bf16x8 val = *(const bf16x8*)&smem[col * 256 +
                         (r8 ^ (((col >> 2) & 3) << 4))];
            int h = h0 + (col >> 6), dh = col & 63;
            *(bf16x8*)&Vt[(((size_t)b * 16 + h) * 64 + dh) * 1024 + s0 + r8] = val;
        }
    } else {
        // straddle (bn=1920): cols 0-127 QK direct; cols 128-191 V transposed
        #pragma unroll
        for (int mi = 0; mi < 4; ++mi)
            #pragma unroll
            for (int nj = 0; nj < 3; ++nj)
                #pragma unroll
                for (int r = 0; r < 4; ++r) {
                    int row = wr * 64 + mi * 16 + quad * 4 + r;
                    int col = wc * 48 + nj * 16 + l15;
                    unsigned short v = f2bf(acc[mi][nj][r] + bv[nj]);
                    if (col < 128)
                        smem[row * 128 + (col ^ (((row >> 2) & 3) << 4))] = v;
                    else {
                        int vc = col - 128;
                        smem[32768 + vc * 256 + (row ^ (((vc >> 2) & 3) << 4))] = v;
                    }
                }
        __syncthreads();
        #pragma unroll
        for (int it = 0; it < 4; ++it) {         // QK: 256x128 = 4096 chunks
            int chunk = it * 1024 + t;
            int row = chunk >> 4;
            int col = (chunk & 15) * 8;
            bf16x8 val = *(const bf16x8*)&smem[row * 128 +
                         (col ^ (((row >> 2) & 3) << 4))];
            *(bf16x8*)&Cout[(size_t)(bm + row) * N + bn + col] = val;
        }
        #pragma unroll
        for (int it = 0; it < 2; ++it) {         // V: 64x256 = 2048 chunks
            int chunk = it * 1024 + t;
            int vc = chunk >> 5;                 // 0..63 -> dh
            int r8 = (chunk & 31) * 8;
            bf16x8 val = *(const bf16x8*)&smem[32768 + vc * 256 +
                         (r8 ^ (((vc >> 2) & 3) << 4))];
            *(bf16x8*)&Vt[(((size_t)b * 16 + 0) * 64 + vc) * 1024 + s0 + r8] = val;
        }
    }
}

// ---------------------------------------------------------------------------
// Output-projection GEMM (R30): same 64x128 tile / triple-buffer / fragment-
// linear staging, but 512 THREADS = 8 waves -> 4 waves/SIMD at 2 blocks/CU
// (was 2/SIMD) — the mechanism proven on gemm1 in R12 (+waves = latency
// hiding). Wave grid 2M x 4N, acc[2][2]; staging A by waves 0-3, B by all
// 8 (one glds16 each); counted per-wave vmcnt 4/2 -> 2/1 -> 0 (exact
// proportional analog of the proven VM(6)/(3)/(0) ledger).
// LDS 36 KB x 2 blocks = 72 KB; fp32 epilogue 32 KB fits.
// ---------------------------------------------------------------------------
__global__ __launch_bounds__(512) void gemm2_mfma(
    const unsigned short* __restrict__ A,
    const unsigned short* __restrict__ Bt,
    const float* __restrict__ bias,
    float* __restrict__ C,
    int N, int K)
{
    __shared__ unsigned short smem[18432];   // 3 bufs x 12 KB

    const int t = threadIdx.x;
    const int lane = t & 63;
    const int w = t >> 6;                    // 0..7
    const int l15 = lane & 15, quad = lane >> 4;

    const int flat = XCD_REMAP(blockIdx.y * 8 + blockIdx.x, 512);
    const int bm = (flat / 8) * 64, bn = (flat % 8) * 128;

    const int fragoff = l15 * K + quad * 8;

    const f32x4 zero4 = {0.f, 0.f, 0.f, 0.f};
    f32x4 acc[2][2];
    #pragma unroll
    for (int i = 0; i < 2; ++i)
        #pragma unroll
        for (int j = 0; j < 2; ++j) acc[i][j] = zero4;

    const unsigned short* Abase = A  + (size_t)bm * K + fragoff;
    const unsigned short* Bbase = Bt + (size_t)bn * K + fragoff;

    const int R = K / 32;

    // A: 4 groups of 512 shorts (rows 0-63) staged by waves 0-3;
    // B: 8 groups (cols 0-127) staged by all 8 waves, one glds16 each.
    auto issue = [&](int k, int b) {
        if (w < 4)
            glds16(Abase + (size_t)(w * 16) * K + k * 32,
                   &smem[b * 6144 + w * 512]);
        glds16(Bbase + (size_t)(w * 16) * K + k * 32,
               &smem[b * 6144 + 2048 + w * 512]);
    };

    issue(0, 0);
    issue(1, 1);
    for (int k = 0; k < R; ++k) {
        if (k + 2 < R) {
            issue(k + 2, (k + 2) % 3);
            if (w < 4) __builtin_amdgcn_s_waitcnt(WAITCNT_VM(4));
            else       __builtin_amdgcn_s_waitcnt(WAITCNT_VM(2));
        } else if (k + 1 < R) {
            if (w < 4) __builtin_amdgcn_s_waitcnt(WAITCNT_VM(2));
            else       __builtin_amdgcn_s_waitcnt(WAITCNT_VM(1));
        } else {
            __builtin_amdgcn_s_waitcnt(WAITCNT_VM(0));
        }
        __builtin_amdgcn_s_barrier();

        bf16x8 af[2], bfr[2];
        #pragma unroll
        for (int mi = 0; mi < 2; ++mi)
            af[mi] = *(const bf16x8*)&smem[(k % 3) * 6144 + ((w >> 2) * 2 + mi) * 512 + lane * 8];
        #pragma unroll
        for (int nj = 0; nj < 2; ++nj)
            bfr[nj] = *(const bf16x8*)&smem[(k % 3) * 6144 + 2048 + ((w & 3) * 2 + nj) * 512 + lane * 8];
        #pragma unroll
        for (int mi = 0; mi < 2; ++mi)
            #pragma unroll
            for (int nj = 0; nj < 2; ++nj)
                acc[mi][nj] = __builtin_amdgcn_mfma_f32_16x16x32_bf16(
                    af[mi], bfr[nj], acc[mi][nj], 0, 0, 0);

        __builtin_amdgcn_s_barrier();
    }

    const int wm = (w >> 2) * 32;
    const int wn = (w & 3) * 32;
    float bv[2];
    #pragma unroll
    for (int nj = 0; nj < 2; ++nj) bv[nj] = bias[bn + wn + nj * 16 + l15];

    float* fs = (float*)smem;
    #pragma unroll
    for (int mi = 0; mi < 2; ++mi)
        #pragma unroll
        for (int nj = 0; nj < 2; ++nj)
            #pragma unroll
            for (int r = 0; r < 4; ++r)
                fs[(wm + mi * 16 + quad * 4 + r) * 128 + wn + nj * 16 + l15] =
                    acc[mi][nj][r] + bv[nj];
    __syncthreads();
    #pragma unroll
    for (int i = 0; i < 4; ++i) {
        int off = i * 512 + t;
        int row = off >> 5, col = (off & 31) * 4;
        *(float4*)&C[(size_t)(bm + row) * N + bn + col] =
            *(const float4*)&fs[row * 128 + col];
    }
}

// ---------------------------------------------------------------------------
// Flash attention (R26, proven): DOUBLE-BUFFERED K/V LDS, one barrier/round.
// ---------------------------------------------------------------------------
__device__ __forceinline__ void attn_tile_step8(
    bf16x8 q0, bf16x8 q1, float* lsum, f32x4* o,
    const unsigned short (*Ks)[80], const unsigned short (*VsT)[80],
    unsigned short (*Ps)[80],
    int wq, int l15, int quad, bool diag)
{
    const f32x4 zero4 = {0.f, 0.f, 0.f, 0.f};
    // S = Q K^T
    f32x4 s[4];
    #pragma unroll
    for (int nj = 0; nj < 4; ++nj) {
        int n = nj * 16 + l15;
        f32x4 sa = zero4;
        bf16x8 b0 = *(const bf16x8*)&Ks[n][swz(n, quad * 8)];
        bf16x8 b1 = *(const bf16x8*)&Ks[n][swz(n, 32 + quad * 8)];
        sa = __builtin_amdgcn_mfma_f32_16x16x32_bf16(q0, b0, sa, 0, 0, 0);
        sa = __builtin_amdgcn_mfma_f32_16x16x32_bf16(q1, b1, sa, 0, 0, 0);
        s[nj] = sa;
    }
    const float scale = 0.125f;  // 1/sqrt(64)

    // p = exp(s*scale); masked -> 0. Lane-private l partials (no shfl here).
    #pragma unroll
    for (int nj = 0; nj < 4; ++nj)
        #pragma unroll
        for (int r = 0; r < 4; ++r) {
            float sv = s[nj][r] * scale;
            if (diag && (nj * 16 + l15) > (wq * 16 + quad * 4 + r)) sv = -INFINITY;
            float p = __expf(sv);
            lsum[r] += p;
            int qloc = wq * 16 + quad * 4 + r;
            Ps[qloc][swz(qloc, nj * 16 + l15)] = f2bf(p);
        }

    // O += P @ V
    #pragma unroll
    for (int kk = 0; kk < 2; ++kk) {
        int m = wq * 16 + l15;
        bf16x8 pa = *(const bf16x8*)&Ps[m][swz(m, kk * 32 + quad * 8)];
        #pragma unroll
        for (int nj = 0; nj < 4; ++nj) {
            int n = nj * 16 + l15;
            bf16x8 vb = *(const bf16x8*)&VsT[n][swz(n, kk * 32 + quad * 8)];
            o[nj] = __builtin_amdgcn_mfma_f32_16x16x32_bf16(pa, vb, o[nj], 0, 0, 0);
        }
    }
}

__global__ __launch_bounds__(512) void attn_mfma(
    const unsigned short* __restrict__ qkv,  // [B*S][3072] bf16
    const unsigned short* __restrict__ Vt,   // [bh][64][1024] bf16
    unsigned short* __restrict__ aout)       // [B*S][1024] bf16
{
    __shared__ unsigned short Ks[2][64][80];   // 20 KB (double-buffered)
    __shared__ unsigned short VsT[2][64][80];  // 20 KB (double-buffered)
    __shared__ unsigned short Ps[2][64][80];   // 20 KB (per tile-group)

    const int t = threadIdx.x;
    const int lane = t & 63;
    const int wave = t >> 6;           // 0..7
    const int wq = wave & 3;
    const int tile = wave >> 2;        // 0 = qlo, 1 = qhi
    const int l15 = lane & 15, quad = lane >> 4;

    const int flat = XCD_REMAP(blockIdx.y * 8 + blockIdx.x, 512);
    const int qlo = flat % 8;          // 0..7
    const int bh = flat / 8;           // 0..63

    const int qhi = 15 - qlo;          // 15..8
    const int qb = tile ? qhi : qlo;
    const int b = bh >> 4, h = bh & 15;
    const size_t qkvbase = (size_t)b * SS * 3072;
    const f32x4 zero4 = {0.f, 0.f, 0.f, 0.f};

    bf16x8 qf0, qf1;
    {
        const unsigned short* p = qkv + qkvbase +
            (size_t)(qb * 64 + wq * 16 + l15) * 3072 + h * 64 + quad * 8;
        qf0 = *(const bf16x8*)p;
        qf1 = *(const bf16x8*)(p + 32);
    }

    float lsum[4];
    f32x4 o[4];
    #pragma unroll
    for (int r = 0; r < 4; ++r) lsum[r] = 0.f;
    #pragma unroll
    for (int nj = 0; nj < 4; ++nj) o[nj] = zero4;

    // register-prefetch staging: 512 threads cover 64x64 in one 16B op each
    const int sr = t >> 3, scc = (t & 7) * 8;
    const unsigned short* kgp = qkv + qkvbase + 1024 + h * 64 + (size_t)sr * 3072 + scc;
    const unsigned short* vgp = Vt + ((size_t)bh * 64 + sr) * 1024 + scc;
    const int klds = swz(sr, scc);     // same swizzled offset for K and V rows
    bf16x8 kreg, vreg;

    // prologue: round 0 into buf0; prefetch round 1 (qhi >= 8 always)
    kreg = *(const bf16x8*)(kgp);
    vreg = *(const bf16x8*)(vgp);
    *(bf16x8*)&Ks[0][sr][klds] = kreg;
    *(bf16x8*)&VsT[0][sr][klds] = vreg;
    kreg = *(const bf16x8*)(kgp + (size_t)64 * 3072);
    vreg = *(const bf16x8*)(vgp + 64);
    __builtin_amdgcn_s_waitcnt(WAITCNT_LGKM0);
    __builtin_amdgcn_s_barrier();

    for (int kb = 0; kb <= qhi; ++kb) {
        const int cur = kb & 1;
        if (kb < qhi) {
            // write prefetched round kb+1 into the other buffer (its last
            // readers were round kb-1 — protected by the trailing barrier)
            *(bf16x8*)&Ks[cur ^ 1][sr][klds] = kreg;
            *(bf16x8*)&VsT[cur ^ 1][sr][klds] = vreg;
            if (kb + 1 < qhi) {                // issue round kb+2 loads
                kreg = *(const bf16x8*)(kgp + (size_t)(kb + 2) * 64 * 3072);
                vreg = *(const bf16x8*)(vgp + (kb + 2) * 64);
            }
        }
        if (kb <= qb)
            attn_tile_step8(qf0, qf1, lsum, o, Ks[cur], VsT[cur], Ps[tile],
                            wq, l15, quad, kb == qb);
        __builtin_amdgcn_s_waitcnt(WAITCNT_LGKM0);  // writes visible
        __builtin_amdgcn_s_barrier();               // one barrier per round
    }

    // deferred l-reduction: one shfl pass over the 16 l15 lanes
    #pragma unroll
    for (int off = 1; off < 16; off <<= 1)
        #pragma unroll
        for (int r = 0; r < 4; ++r)
            lsum[r] += __shfl_xor(lsum[r], off);

    // epilogue: normalize, write merge-heads bf16 [B*S][1024]
    #pragma unroll
    for (int r = 0; r < 4; ++r) {
        float inv = 1.0f / lsum[r];
        int rloc = wq * 16 + quad * 4 + r;
        size_t ob = ((size_t)b * SS + qb * 64 + rloc) * 1024 + h * 64;
        #pragma unroll
        for (int nj = 0; nj < 4; ++nj)
            aout[ob + nj * 16 + l15] = f2bf(o[nj][r] * inv);
    }
}

extern "C" void kernel_launch(void* const* d_in, const int* in_sizes, int n_in,
                              void* d_out, int out_size, void* d_ws, size_t ws_size,
                              hipStream_t stream)
{
    const float* x     = (const float*)d_in[0];
    const float* wqkv  = (const float*)d_in[1];
    const float* bqkv  = (const float*)d_in[2];
    const float* wproj = (const float*)d_in[3];
    const float* bproj = (const float*)d_in[4];
    float* out = (float*)d_out;

    unsigned short* ws   = (unsigned short*)d_ws;
    unsigned short* Xb   = ws;                                  // 4096*1024
    unsigned short* W1t  = Xb  + (size_t)4096 * 1024;           // 3072*1024
    unsigned short* W2t  = W1t + (size_t)3072 * 1024;           // 1024*1024
    unsigned short* qkv  = W2t + (size_t)1024 * 1024;           // 4096*3072 (V third unused)
    unsigned short* Vt   = qkv + (size_t)4096 * 3072;           // 64*64*1024
    unsigned short* abuf = Vt  + (size_t)64 * 64 * 1024;        // 4096*1024

    prologue_kernel<<<5120, 256, 0, stream>>>(x, wqkv, wproj, Xb, W1t, W2t);

    // QKV projection: 256x192 tile, 1024 threads (R12-proven, R13 reverted)
    gemm_mfma<<<dim3(16, 16), 1024, 0, stream>>>(
        Xb, W1t, bqkv, qkv, Vt, 3072, 1024);

    // 8-wave attention: K/V double-buffered, one barrier per round
    attn_mfma<<<dim3(8, 64), 512, 0, stream>>>(qkv, Vt, abuf);

    // Output projection: 512 threads (8 waves), triple-buffered, 2 blocks/CU
    gemm2_mfma<<<dim3(1024 / 128, 4096 / 64), 512, 0, stream>>>(
        abuf, W2t, bproj, out, 1024, 1024);
}